// Round 14
// baseline (101.067 us; speedup 1.0000x reference)
//
#include <hip/hip_runtime.h>
#include <cstdint>

#define D_MODEL 768
#define NH      12
#define DKH     64
#define SEQ     2048
#define BS      2
#define MROWS   (BS*SEQ)   // 4096

typedef __bf16 bf16x8 __attribute__((ext_vector_type(8)));
typedef float  f32x4  __attribute__((ext_vector_type(4)));
typedef unsigned int u32_as1 __attribute__((address_space(1)));
typedef unsigned int u32_as3 __attribute__((address_space(3)));

__device__ __forceinline__ void gld16(const void* g, void* l) {
  __builtin_amdgcn_global_load_lds((const u32_as1*)g, (u32_as3*)l, 16, 0, 0);
}
__device__ __forceinline__ unsigned short f2bf(float x) {
  return __builtin_bit_cast(unsigned short, (__bf16)x);
}

// ---------------- fused convert kernel (q, c, 4 weights) ---------------------
// blocks [0,3072): query ; [3072,6144): context ; [6144,8448): 4 weights
// (576 blocks each). Section offsets via subtraction (3072 not a pow2!).
__global__ void cvt_all(
    const float* __restrict__ q, const float* __restrict__ c,
    const float* __restrict__ wq, const float* __restrict__ wk,
    const float* __restrict__ wv, const float* __restrict__ wf,
    unsigned short* __restrict__ oq, unsigned short* __restrict__ oc,
    unsigned short* __restrict__ owq, unsigned short* __restrict__ owk,
    unsigned short* __restrict__ owv, unsigned short* __restrict__ owf)
{
  const int b = blockIdx.x;
  const float* in; unsigned short* out; int i;
  if (b < 6144) {
    in = (b < 3072) ? q : c;
    out = (b < 3072) ? oq : oc;
    i = ((b < 3072) ? b : b - 3072) * 256 + threadIdx.x;
  } else {
    int wb = b - 6144, wi = wb / 576;
    in  = (wi == 0) ? wq : (wi == 1) ? wk : (wi == 2) ? wv : wf;
    out = (wi == 0) ? owq : (wi == 1) ? owk : (wi == 2) ? owv : owf;
    i = (wb - wi * 576) * 256 + threadIdx.x;
  }
  float4 v = reinterpret_cast<const float4*>(in)[i];
  ushort4 o; o.x = f2bf(v.x); o.y = f2bf(v.y); o.z = f2bf(v.z); o.w = f2bf(v.w);
  reinterpret_cast<ushort4*>(out)[i] = o;
}

// cmask (int) -> bf16 mask vector for the accL MFMA B-operand
__global__ void mask_bf(const int* __restrict__ m, unsigned short* __restrict__ o) {
  int i = blockIdx.x * 256 + threadIdx.x;   // 4096 total
  o[i] = f2bf(m[i] ? 1.0f : 0.0f);
}

// ---------------- 64x128 NT GEMM body (K=768), dbuf, 1 barrier/K-step -------
// C[m,n] = (sum_k A[m,k]*B[n,k] + bias) * outScale * (colMask?colMask[col]:1)
template<bool OUT_F32>
__device__ __forceinline__ void gemm64x128_body(
    const unsigned short* __restrict__ A, const unsigned short* __restrict__ B,
    const float* __restrict__ bias, int biasRow, void* __restrict__ Cout,
    int ldc, int m0, int n0, float outScale, const int* __restrict__ colMask)
{
  __shared__ alignas(16) char sA[2][8192];    // 64 rows x 128B
  __shared__ alignas(16) char sB[2][16384];   // 128 rows x 128B
  const int tid = threadIdx.x;
  const int w = tid >> 6, l = tid & 63;
  const int g16 = l >> 4, c16 = l & 15;
  const int wr = (w >> 1) * 32, wc = (w & 1) * 64;

  auto stageA = [&](int kt, char* dst) {
#pragma unroll
    for (int i = 0; i < 2; i++) {
      int ch = w * 2 + i;
      int X = ch * 1024 + l * 16;
      int row = X >> 7;
      int sl = ((X >> 4) & 7) ^ (row & 7);
      gld16(A + (size_t)(m0 + row) * 768 + kt + sl * 8, dst + ch * 1024);
    }
  };
  auto stageB = [&](int kt, char* dst) {
#pragma unroll
    for (int i = 0; i < 4; i++) {
      int ch = w * 4 + i;
      int X = ch * 1024 + l * 16;
      int row = X >> 7;
      int sl = ((X >> 4) & 7) ^ (row & 7);
      gld16(B + (size_t)(n0 + row) * 768 + kt + sl * 8, dst + ch * 1024);
    }
  };

  f32x4 acc[2][4];
#pragma unroll
  for (int m = 0; m < 2; m++)
#pragma unroll
    for (int n = 0; n < 4; n++) acc[m][n] = f32x4{0.f, 0.f, 0.f, 0.f};

  stageA(0, sA[0]);
  stageB(0, sB[0]);
  __syncthreads();
  int cur = 0;
  for (int kt = 0; kt < 768; kt += 64) {
    if (kt + 64 < 768) {
      stageA(kt + 64, sA[cur ^ 1]);
      stageB(kt + 64, sB[cur ^ 1]);
    }
    __builtin_amdgcn_s_setprio(1);
#pragma unroll
    for (int kk = 0; kk < 2; kk++) {
      bf16x8 af[2], bq[4];
#pragma unroll
      for (int m = 0; m < 2; m++) {
        int row = wr + m * 16 + c16, slot = kk * 4 + g16;
        af[m] = *(const bf16x8*)(sA[cur] + row * 128 + ((slot ^ (row & 7)) << 4));
      }
#pragma unroll
      for (int n = 0; n < 4; n++) {
        int row = wc + n * 16 + c16, slot = kk * 4 + g16;
        bq[n] = *(const bf16x8*)(sB[cur] + row * 128 + ((slot ^ (row & 7)) << 4));
      }
#pragma unroll
      for (int m = 0; m < 2; m++)
#pragma unroll
        for (int n = 0; n < 4; n++)
          acc[m][n] = __builtin_amdgcn_mfma_f32_16x16x32_bf16(af[m], bq[n], acc[m][n], 0, 0, 0);
    }
    __builtin_amdgcn_s_setprio(0);
    __syncthreads();
    cur ^= 1;
  }

#pragma unroll
  for (int m = 0; m < 2; m++)
#pragma unroll
    for (int n = 0; n < 4; n++)
#pragma unroll
      for (int r = 0; r < 4; r++) {
        int row = m0 + wr + m * 16 + g16 * 4 + r;
        int col = n0 + wc + n * 16 + c16;
        float v = (acc[m][n][r] + (biasRow ? bias[row] : bias[col])) * outScale;
        if (colMask) v *= (float)colMask[col];
        if constexpr (OUT_F32) ((float*)Cout)[(size_t)row * ldc + col] = v;
        else ((unsigned short*)Cout)[(size_t)row * ldc + col] = f2bf(v);
      }
}

// scale*log2(e) folded into Q so attn softmax uses raw v_exp_f32
#define QSCALE 0.1803368801111f   // 0.125 * log2(e)

// Fused QKV projections: grid dim3(384, 3); x XCD-swizzled (384 = 48 x 8).
__global__ __launch_bounds__(256, 2) void gemm_qkv(
    const unsigned short* __restrict__ q_bf, const unsigned short* __restrict__ c_bf,
    const unsigned short* __restrict__ wq, const unsigned short* __restrict__ wk,
    const unsigned short* __restrict__ wv,
    const float* __restrict__ bq, const float* __restrict__ bk,
    const float* __restrict__ bv, const int* __restrict__ cmask,
    unsigned short* __restrict__ Qb, unsigned short* __restrict__ Kb,
    unsigned short* __restrict__ Vtb)
{
  const int x = blockIdx.x;
  const int lin = (x & 7) * 48 + (x >> 3);   // bijective 0..383
  if (blockIdx.y == 0) {
    gemm64x128_body<false>(q_bf, wq, bq, 0, Qb, 768, (lin / 6) * 64, (lin % 6) * 128,
                           QSCALE, nullptr);
  } else if (blockIdx.y == 1) {
    gemm64x128_body<false>(c_bf, wk, bk, 0, Kb, 768, (lin / 6) * 64, (lin % 6) * 128,
                           1.0f, nullptr);
  } else {
    gemm64x128_body<false>(wv, c_bf, bv, 1, Vtb, 4096, (lin % 12) * 64, (lin / 12) * 128,
                           1.0f, cmask);
  }
}

// ---------------- 64x64 NT GEMM for fc (grid 768, 3 blocks/CU) ---------------
__global__ __launch_bounds__(256, 4) void gemm_fc64(
    const unsigned short* __restrict__ A, const unsigned short* __restrict__ B,
    const float* __restrict__ bias, float* __restrict__ Cout)
{
  __shared__ alignas(16) char sA[2][8192];   // 64 rows x 128B, XOR-swizzled
  __shared__ alignas(16) char sB[2][8192];
  const int tid = threadIdx.x;
  const int w = tid >> 6, l = tid & 63;
  const int g16 = l >> 4, c16 = l & 15;
  const int flat = blockIdx.x;
  const int lin = (flat & 7) * 96 + (flat >> 3);   // bijective: xcd*96 + idx
  const int tf = lin % 12, ts = lin / 12;
  const int m0 = ts * 64, n0 = tf * 64;
  const int wr = (w >> 1) * 32, wc = (w & 1) * 32;

  auto stage = [&](const unsigned short* __restrict__ P, int p0, int kt, char* dst) {
#pragma unroll
    for (int i = 0; i < 2; i++) {
      int ch = w * 2 + i;
      int X = ch * 1024 + l * 16;
      int row = X >> 7;
      int sl = ((X >> 4) & 7) ^ (row & 7);
      gld16(P + (size_t)(p0 + row) * 768 + kt + sl * 8, dst + ch * 1024);
    }
  };

  f32x4 acc[2][2];
#pragma unroll
  for (int m = 0; m < 2; m++)
#pragma unroll
    for (int n = 0; n < 2; n++) acc[m][n] = f32x4{0.f, 0.f, 0.f, 0.f};

  stage(A, m0, 0, sA[0]);
  stage(B, n0, 0, sB[0]);
  __syncthreads();
  int cur = 0;
  for (int kt = 0; kt < 768; kt += 64) {
    if (kt + 64 < 768) {
      stage(A, m0, kt + 64, sA[cur ^ 1]);
      stage(B, n0, kt + 64, sB[cur ^ 1]);
    }
    __builtin_amdgcn_s_setprio(1);
#pragma unroll
    for (int kk = 0; kk < 2; kk++) {
      bf16x8 af[2], bq[2];
#pragma unroll
      for (int m = 0; m < 2; m++) {
        int row = wr + m * 16 + c16, slot = kk * 4 + g16;
        af[m] = *(const bf16x8*)(sA[cur] + row * 128 + ((slot ^ (row & 7)) << 4));
      }
#pragma unroll
      for (int n = 0; n < 2; n++) {
        int row = wc + n * 16 + c16, slot = kk * 4 + g16;
        bq[n] = *(const bf16x8*)(sB[cur] + row * 128 + ((slot ^ (row & 7)) << 4));
      }
#pragma unroll
      for (int m = 0; m < 2; m++)
#pragma unroll
        for (int n = 0; n < 2; n++)
          acc[m][n] = __builtin_amdgcn_mfma_f32_16x16x32_bf16(af[m], bq[n], acc[m][n], 0, 0, 0);
    }
    __builtin_amdgcn_s_setprio(0);
    __syncthreads();
    cur ^= 1;
  }

#pragma unroll
  for (int m = 0; m < 2; m++)
#pragma unroll
    for (int n = 0; n < 2; n++)
#pragma unroll
      for (int r = 0; r < 4; r++) {
        int row = m0 + wr + m * 16 + g16 * 4 + r;
        int col = n0 + wc + n * 16 + c16;
        Cout[(size_t)row * 768 + col] = acc[m][n][r] + bias[col];
      }
}

// ---------------- flash attention: 2-wave blocks, 32 q-rows/wave -------------
// Grid 768 (same XCD decode as r10: 24 panels x 32 qtiles of 64 rows), but
// each block is 2 waves x 32 q-rows (m-rep 2). LDS traffic per 64 q-rows per
// c-tile: 64KB vs r10's 96KB (kf/vf amortized over 2x the q-rows), while
// KEEPING grid 768 = 3 blocks/CU (r11's m-rep-2 failed at grid 384 = 1.5/CU).
// LDS 40KB; barriers sync only 2 waves. Softmax/mask scheme = r10.
__global__ __launch_bounds__(128, 2) void attn_kernel(
    const unsigned short* __restrict__ Qb, const unsigned short* __restrict__ Kb,
    const unsigned short* __restrict__ Vt, const unsigned short* __restrict__ maskbf,
    unsigned short* __restrict__ Ob)
{
  __shared__ alignas(16) char sK[2][8192];   // 64 x 64 bf16, swizzled rows
  __shared__ alignas(16) char sV[2][8192];   // 64(dv) x 64(c)
  __shared__ alignas(16) char sP[8192];      // 2 waves x 32 rows x 128B
  const int tid = threadIdx.x, w = tid >> 6, l = tid & 63;   // w in {0,1}
  const int g16 = l >> 4, c16 = l & 15;
  const int flat = blockIdx.x;                 // 768
  const int xcd = flat & 7, sidx = flat >> 3;  // sidx 0..95
  const int p = xcd + 8 * (sidx >> 5);         // panel 0..23
  const int qt = sidx & 31;                    // qtile (64 rows)
  const int h = p % 12, b = p / 12;
  const int qrow0 = b * SEQ + qt * 64;
  const int crow0 = b * SEQ;

  // Q fragments, 2 m-reps: q-row = w*32 + m*16 + c16
  bf16x8 qa[2][2];
#pragma unroll
  for (int m = 0; m < 2; m++) {
    const unsigned short* qp =
        Qb + (size_t)(qrow0 + w * 32 + m * 16 + c16) * D_MODEL + h * DKH + g16 * 8;
    qa[m][0] = *(const bf16x8*)(qp);
    qa[m][1] = *(const bf16x8*)(qp + 32);
  }

  auto stageK = [&](int ct, int buf) {
#pragma unroll
    for (int i = 0; i < 4; i++) {
      int ch = w * 4 + i;                      // 8 chunks over 2 waves
      int X = ch * 1024 + l * 16;
      int row = X >> 7;
      int sl = ((X >> 4) & 7) ^ (row & 7);
      gld16(Kb + (size_t)(crow0 + ct + row) * D_MODEL + h * DKH + sl * 8,
            sK[buf] + ch * 1024);
    }
  };
  auto stageV = [&](int ct, int buf) {
#pragma unroll
    for (int i = 0; i < 4; i++) {
      int ch = w * 4 + i;
      int X = ch * 1024 + l * 16;
      int row = X >> 7;
      int sl = ((X >> 4) & 7) ^ (row & 7);
      gld16(Vt + (size_t)(h * DKH + row) * (size_t)MROWS + crow0 + ct + sl * 8,
            sV[buf] + ch * 1024);
    }
  };

  f32x4 accO[2][4], accL[2];
#pragma unroll
  for (int m = 0; m < 2; m++) {
#pragma unroll
    for (int n = 0; n < 4; n++) accO[m][n] = f32x4{0.f, 0.f, 0.f, 0.f};
    accL[m] = f32x4{0.f, 0.f, 0.f, 0.f};
  }

  stageK(0, 0); stageV(0, 0);
  __syncthreads();
  int cur = 0;

  for (int ct = 0; ct < SEQ; ct += 64) {
    if (ct + 64 < SEQ) { stageK(ct + 64, cur ^ 1); stageV(ct + 64, cur ^ 1); }

    // bf16 mask fragments for accL (L1/L2-resident)
    bf16x8 mfrag[2];
#pragma unroll
    for (int kk = 0; kk < 2; kk++)
      mfrag[kk] = *(const bf16x8*)(maskbf + crow0 + ct + kk * 32 + g16 * 8);

    // S = Q K^T : kf read once per kk, reused by both m-reps
    f32x4 s[2][4];
#pragma unroll
    for (int m = 0; m < 2; m++)
#pragma unroll
      for (int n = 0; n < 4; n++) s[m][n] = f32x4{0.f, 0.f, 0.f, 0.f};
    __builtin_amdgcn_s_setprio(1);
#pragma unroll
    for (int kk = 0; kk < 2; kk++) {
      bf16x8 kf[4];
#pragma unroll
      for (int n = 0; n < 4; n++) {
        int row = n * 16 + c16, slot = kk * 4 + g16;
        kf[n] = *(const bf16x8*)(sK[cur] + row * 128 + ((slot ^ (row & 7)) << 4));
      }
#pragma unroll
      for (int m = 0; m < 2; m++)
#pragma unroll
        for (int n = 0; n < 4; n++)
          s[m][n] = __builtin_amdgcn_mfma_f32_16x16x32_bf16(qa[m][kk], kf[n], s[m][n], 0, 0, 0);
    }
    __builtin_amdgcn_s_setprio(0);

    // softmax numerator: p = exp2(s) -> per-wave sP (32 rows x 128B)
#pragma unroll
    for (int m = 0; m < 2; m++)
#pragma unroll
      for (int r = 0; r < 4; r++) {
        int prow = m * 16 + g16 * 4 + r;
#pragma unroll
        for (int n = 0; n < 4; n++) {
          float pv = __builtin_amdgcn_exp2f(s[m][n][r]);
          int slot = n * 2 + (c16 >> 3);
          int addr = w * 4096 + prow * 128 + ((slot ^ (prow & 7)) << 4) + (c16 & 7) * 2;
          *(__bf16*)(sP + addr) = (__bf16)pv;
        }
      }

    // O += P * V(masked) ; L += P * maskfrag. vf read once per kk, reused.
    __builtin_amdgcn_s_setprio(1);
#pragma unroll
    for (int kk = 0; kk < 2; kk++) {
      bf16x8 pa[2], vf[4];
#pragma unroll
      for (int m = 0; m < 2; m++) {
        int prow = m * 16 + c16, slot = kk * 4 + g16;
        pa[m] = *(const bf16x8*)(sP + w * 4096 + prow * 128 + ((slot ^ (prow & 7)) << 4));
      }
#pragma unroll
      for (int n = 0; n < 4; n++) {
        int vrow = n * 16 + c16, slot = kk * 4 + g16;
        vf[n] = *(const bf16x8*)(sV[cur] + vrow * 128 + ((slot ^ (vrow & 7)) << 4));
      }
#pragma unroll
      for (int m = 0; m < 2; m++) {
#pragma unroll
        for (int n = 0; n < 4; n++)
          accO[m][n] = __builtin_amdgcn_mfma_f32_16x16x32_bf16(pa[m], vf[n], accO[m][n], 0, 0, 0);
        accL[m] = __builtin_amdgcn_mfma_f32_16x16x32_bf16(pa[m], mfrag[kk], accL[m], 0, 0, 0);
      }
    }
    __builtin_amdgcn_s_setprio(0);

    __syncthreads();
    cur ^= 1;
  }

#pragma unroll
  for (int m = 0; m < 2; m++)
#pragma unroll
    for (int r = 0; r < 4; r++) {
      float inv = 1.0f / accL[m][r];
#pragma unroll
      for (int n = 0; n < 4; n++) {
        int row = qrow0 + w * 32 + m * 16 + g16 * 4 + r;
        int col = h * DKH + n * 16 + c16;
        Ob[(size_t)row * D_MODEL + col] = f2bf(accO[m][n][r] * inv);
      }
    }
}

// ---------------- launcher --------------------------------------------------
extern "C" void kernel_launch(void* const* d_in, const int* in_sizes, int n_in,
                              void* d_out, int out_size, void* d_ws, size_t ws_size,
                              hipStream_t stream) {
  const float* query   = (const float*)d_in[0];
  const float* context = (const float*)d_in[1];
  const int*   cmask   = (const int*)d_in[2];
  const float* Wq_w = (const float*)d_in[3];
  const float* Wq_b = (const float*)d_in[4];
  const float* Wk_w = (const float*)d_in[5];
  const float* Wk_b = (const float*)d_in[6];
  const float* Wv_w = (const float*)d_in[7];
  const float* Wv_b = (const float*)d_in[8];
  const float* fc_w = (const float*)d_in[9];
  const float* fc_b = (const float*)d_in[10];
  float* out = (float*)d_out;

  unsigned short* ws   = (unsigned short*)d_ws;
  const size_t NQ = (size_t)MROWS * D_MODEL;
  const size_t NW = (size_t)D_MODEL * D_MODEL;
  unsigned short* q_bf = ws;
  unsigned short* c_bf = q_bf + NQ;
  unsigned short* Qb   = c_bf + NQ;
  unsigned short* Kb   = Qb + NQ;
  unsigned short* Vtb  = Kb + NQ;
  unsigned short* Ob   = Vtb + NQ;
  unsigned short* wq   = Ob + NQ;
  unsigned short* wk   = wq + NW;
  unsigned short* wv   = wk + NW;
  unsigned short* wf   = wv + NW;
  // q_bf is dead after gemm_qkv; reuse its head for the bf16 mask vector
  unsigned short* maskbf = q_bf;   // 4096 bf16 = 8KB

  // one fused convert launch: q, c, 4 weights
  cvt_all<<<8448, 256, 0, stream>>>(query, context, Wq_w, Wk_w, Wv_w, fc_w,
                                    q_bf, c_bf, wq, wk, wv, wf);

  // Q/K/V projections fused: y=0 Q(scaled), y=1 K, y=2 V^T(col-masked)
  gemm_qkv<<<dim3(384, 3), 256, 0, stream>>>(
      q_bf, c_bf, wq, wk, wv, Wq_b, Wk_b, Wv_b, cmask, Qb, Kb, Vtb);

  // after gemm_qkv, q_bf is dead -> safe to overwrite with maskbf
  mask_bf<<<MROWS / 256, 256, 0, stream>>>(cmask, maskbf);

  attn_kernel<<<768, 128, 0, stream>>>(Qb, Kb, Vtb, maskbf, Ob);

  // out = O @ fc^T + fb (f32), 64x64 tiles, grid 768
  gemm_fc64<<<768, 256, 0, stream>>>(Ob, wf, fc_b, out);
}

// Round 15
// 94.084 us; speedup vs baseline: 1.0742x; 1.0742x over previous
//
#include <hip/hip_runtime.h>
#include <cstdint>

#define D_MODEL 768
#define NH      12
#define DKH     64
#define SEQ     2048
#define BS      2
#define MROWS   (BS*SEQ)   // 4096

typedef __bf16 bf16x8 __attribute__((ext_vector_type(8)));
typedef __bf16 bf16x4 __attribute__((ext_vector_type(4)));
typedef float  f32x4  __attribute__((ext_vector_type(4)));
typedef unsigned int u32_as1 __attribute__((address_space(1)));
typedef unsigned int u32_as3 __attribute__((address_space(3)));

__device__ __forceinline__ void gld16(const void* g, void* l) {
  __builtin_amdgcn_global_load_lds((const u32_as1*)g, (u32_as3*)l, 16, 0, 0);
}
__device__ __forceinline__ unsigned short f2bf(float x) {
  return __builtin_bit_cast(unsigned short, (__bf16)x);
}

// ---------------- fused convert kernel (q, c, 4 weights) ---------------------
// blocks [0,3072): query ; [3072,6144): context ; [6144,8448): 4 weights.
// Section offsets via subtraction (3072 not a pow2!).
__global__ void cvt_all(
    const float* __restrict__ q, const float* __restrict__ c,
    const float* __restrict__ wq, const float* __restrict__ wk,
    const float* __restrict__ wv, const float* __restrict__ wf,
    unsigned short* __restrict__ oq, unsigned short* __restrict__ oc,
    unsigned short* __restrict__ owq, unsigned short* __restrict__ owk,
    unsigned short* __restrict__ owv, unsigned short* __restrict__ owf)
{
  const int b = blockIdx.x;
  const float* in; unsigned short* out; int i;
  if (b < 6144) {
    in = (b < 3072) ? q : c;
    out = (b < 3072) ? oq : oc;
    i = ((b < 3072) ? b : b - 3072) * 256 + threadIdx.x;
  } else {
    int wb = b - 6144, wi = wb / 576;
    in  = (wi == 0) ? wq : (wi == 1) ? wk : (wi == 2) ? wv : wf;
    out = (wi == 0) ? owq : (wi == 1) ? owk : (wi == 2) ? owv : owf;
    i = (wb - wi * 576) * 256 + threadIdx.x;
  }
  float4 v = reinterpret_cast<const float4*>(in)[i];
  ushort4 o; o.x = f2bf(v.x); o.y = f2bf(v.y); o.z = f2bf(v.z); o.w = f2bf(v.w);
  reinterpret_cast<ushort4*>(out)[i] = o;
}

// cmask (int) -> bf16 mask vector for the accL MFMA B-operand
__global__ void mask_bf(const int* __restrict__ m, unsigned short* __restrict__ o) {
  int i = blockIdx.x * 256 + threadIdx.x;   // 4096 total
  o[i] = f2bf(m[i] ? 1.0f : 0.0f);
}

// ---------------- 64x128 NT GEMM body (K=768), dbuf, 1 barrier/K-step -------
template<bool OUT_F32>
__device__ __forceinline__ void gemm64x128_body(
    const unsigned short* __restrict__ A, const unsigned short* __restrict__ B,
    const float* __restrict__ bias, int biasRow, void* __restrict__ Cout,
    int ldc, int m0, int n0, float outScale, const int* __restrict__ colMask)
{
  __shared__ alignas(16) char sA[2][8192];    // 64 rows x 128B
  __shared__ alignas(16) char sB[2][16384];   // 128 rows x 128B
  const int tid = threadIdx.x;
  const int w = tid >> 6, l = tid & 63;
  const int g16 = l >> 4, c16 = l & 15;
  const int wr = (w >> 1) * 32, wc = (w & 1) * 64;

  auto stageA = [&](int kt, char* dst) {
#pragma unroll
    for (int i = 0; i < 2; i++) {
      int ch = w * 2 + i;
      int X = ch * 1024 + l * 16;
      int row = X >> 7;
      int sl = ((X >> 4) & 7) ^ (row & 7);
      gld16(A + (size_t)(m0 + row) * 768 + kt + sl * 8, dst + ch * 1024);
    }
  };
  auto stageB = [&](int kt, char* dst) {
#pragma unroll
    for (int i = 0; i < 4; i++) {
      int ch = w * 4 + i;
      int X = ch * 1024 + l * 16;
      int row = X >> 7;
      int sl = ((X >> 4) & 7) ^ (row & 7);
      gld16(B + (size_t)(n0 + row) * 768 + kt + sl * 8, dst + ch * 1024);
    }
  };

  f32x4 acc[2][4];
#pragma unroll
  for (int m = 0; m < 2; m++)
#pragma unroll
    for (int n = 0; n < 4; n++) acc[m][n] = f32x4{0.f, 0.f, 0.f, 0.f};

  stageA(0, sA[0]);
  stageB(0, sB[0]);
  __syncthreads();
  int cur = 0;
  for (int kt = 0; kt < 768; kt += 64) {
    if (kt + 64 < 768) {
      stageA(kt + 64, sA[cur ^ 1]);
      stageB(kt + 64, sB[cur ^ 1]);
    }
    __builtin_amdgcn_s_setprio(1);
#pragma unroll
    for (int kk = 0; kk < 2; kk++) {
      bf16x8 af[2], bq[4];
#pragma unroll
      for (int m = 0; m < 2; m++) {
        int row = wr + m * 16 + c16, slot = kk * 4 + g16;
        af[m] = *(const bf16x8*)(sA[cur] + row * 128 + ((slot ^ (row & 7)) << 4));
      }
#pragma unroll
      for (int n = 0; n < 4; n++) {
        int row = wc + n * 16 + c16, slot = kk * 4 + g16;
        bq[n] = *(const bf16x8*)(sB[cur] + row * 128 + ((slot ^ (row & 7)) << 4));
      }
#pragma unroll
      for (int m = 0; m < 2; m++)
#pragma unroll
        for (int n = 0; n < 4; n++)
          acc[m][n] = __builtin_amdgcn_mfma_f32_16x16x32_bf16(af[m], bq[n], acc[m][n], 0, 0, 0);
    }
    __builtin_amdgcn_s_setprio(0);
    __syncthreads();
    cur ^= 1;
  }

#pragma unroll
  for (int m = 0; m < 2; m++)
#pragma unroll
    for (int n = 0; n < 4; n++)
#pragma unroll
      for (int r = 0; r < 4; r++) {
        int row = m0 + wr + m * 16 + g16 * 4 + r;
        int col = n0 + wc + n * 16 + c16;
        float v = (acc[m][n][r] + (biasRow ? bias[row] : bias[col])) * outScale;
        if (colMask) v *= (float)colMask[col];
        if constexpr (OUT_F32) ((float*)Cout)[(size_t)row * ldc + col] = v;
        else ((unsigned short*)Cout)[(size_t)row * ldc + col] = f2bf(v);
      }
}

// scale*log2(e) folded into Q so attn softmax uses raw v_exp_f32
#define QSCALE 0.1803368801111f   // 0.125 * log2(e)

// Fused QKV projections: grid dim3(384, 3); x XCD-swizzled (384 = 48 x 8).
__global__ __launch_bounds__(256, 2) void gemm_qkv(
    const unsigned short* __restrict__ q_bf, const unsigned short* __restrict__ c_bf,
    const unsigned short* __restrict__ wq, const unsigned short* __restrict__ wk,
    const unsigned short* __restrict__ wv,
    const float* __restrict__ bq, const float* __restrict__ bk,
    const float* __restrict__ bv, const int* __restrict__ cmask,
    unsigned short* __restrict__ Qb, unsigned short* __restrict__ Kb,
    unsigned short* __restrict__ Vtb)
{
  const int x = blockIdx.x;
  const int lin = (x & 7) * 48 + (x >> 3);   // bijective 0..383
  if (blockIdx.y == 0) {
    gemm64x128_body<false>(q_bf, wq, bq, 0, Qb, 768, (lin / 6) * 64, (lin % 6) * 128,
                           QSCALE, nullptr);
  } else if (blockIdx.y == 1) {
    gemm64x128_body<false>(c_bf, wk, bk, 0, Kb, 768, (lin / 6) * 64, (lin % 6) * 128,
                           1.0f, nullptr);
  } else {
    gemm64x128_body<false>(wv, c_bf, bv, 1, Vtb, 4096, (lin % 12) * 64, (lin / 12) * 128,
                           1.0f, cmask);
  }
}

// ---------------- 64x64 NT GEMM for fc (grid 768, 3 blocks/CU) ---------------
__global__ __launch_bounds__(256, 4) void gemm_fc64(
    const unsigned short* __restrict__ A, const unsigned short* __restrict__ B,
    const float* __restrict__ bias, float* __restrict__ Cout)
{
  __shared__ alignas(16) char sA[2][8192];
  __shared__ alignas(16) char sB[2][8192];
  const int tid = threadIdx.x;
  const int w = tid >> 6, l = tid & 63;
  const int g16 = l >> 4, c16 = l & 15;
  const int flat = blockIdx.x;
  const int lin = (flat & 7) * 96 + (flat >> 3);
  const int tf = lin % 12, ts = lin / 12;
  const int m0 = ts * 64, n0 = tf * 64;
  const int wr = (w >> 1) * 32, wc = (w & 1) * 32;

  auto stage = [&](const unsigned short* __restrict__ P, int p0, int kt, char* dst) {
#pragma unroll
    for (int i = 0; i < 2; i++) {
      int ch = w * 2 + i;
      int X = ch * 1024 + l * 16;
      int row = X >> 7;
      int sl = ((X >> 4) & 7) ^ (row & 7);
      gld16(P + (size_t)(p0 + row) * 768 + kt + sl * 8, dst + ch * 1024);
    }
  };

  f32x4 acc[2][2];
#pragma unroll
  for (int m = 0; m < 2; m++)
#pragma unroll
    for (int n = 0; n < 2; n++) acc[m][n] = f32x4{0.f, 0.f, 0.f, 0.f};

  stage(A, m0, 0, sA[0]);
  stage(B, n0, 0, sB[0]);
  __syncthreads();
  int cur = 0;
  for (int kt = 0; kt < 768; kt += 64) {
    if (kt + 64 < 768) {
      stage(A, m0, kt + 64, sA[cur ^ 1]);
      stage(B, n0, kt + 64, sB[cur ^ 1]);
    }
    __builtin_amdgcn_s_setprio(1);
#pragma unroll
    for (int kk = 0; kk < 2; kk++) {
      bf16x8 af[2], bq[2];
#pragma unroll
      for (int m = 0; m < 2; m++) {
        int row = wr + m * 16 + c16, slot = kk * 4 + g16;
        af[m] = *(const bf16x8*)(sA[cur] + row * 128 + ((slot ^ (row & 7)) << 4));
      }
#pragma unroll
      for (int n = 0; n < 2; n++) {
        int row = wc + n * 16 + c16, slot = kk * 4 + g16;
        bq[n] = *(const bf16x8*)(sB[cur] + row * 128 + ((slot ^ (row & 7)) << 4));
      }
#pragma unroll
      for (int m = 0; m < 2; m++)
#pragma unroll
        for (int n = 0; n < 2; n++)
          acc[m][n] = __builtin_amdgcn_mfma_f32_16x16x32_bf16(af[m], bq[n], acc[m][n], 0, 0, 0);
    }
    __builtin_amdgcn_s_setprio(0);
    __syncthreads();
    cur ^= 1;
  }

#pragma unroll
  for (int m = 0; m < 2; m++)
#pragma unroll
    for (int n = 0; n < 2; n++)
#pragma unroll
      for (int r = 0; r < 4; r++) {
        int row = m0 + wr + m * 16 + g16 * 4 + r;
        int col = n0 + wc + n * 16 + c16;
        Cout[(size_t)row * 768 + col] = acc[m][n][r] + bias[col];
      }
}

// ---------------- flash attention: in-register P (no sP) ---------------------
// r13 grid/occupancy (768 blocks x 4 waves, 16 q-rows/wave, 12 waves/CU) with
// the P LDS round-trip removed. Swapped QK^T (r9-verified): s4[n][r] holds
// S[c = 16n+4*g16+r][q = w*16+c16]. PV uses a RELABELED k-order
// c(g,j) = 32kk + 16*(j>>2) + 4g + (j&3) applied to BOTH operands (MFMA sum
// is invariant under a shared k-permutation):
//   A (P): paf[kk] = {pv[2kk][0..3], pv[2kk+1][0..3]} -- pure lane-local pack
//   B (V): two ds_read_b64 at slots 4kk+(g>>1), +2, sub-offset 8*(g&1)
//   accL:  mask frag in the same k-order (two 8B global loads, L1-resident)
// No-max softmax => no O-rescale => S lane layout (q=c16) never meets O's
// (q=4g+r). Saves 88 of 280 LDS-pipe cyc/wave-tile at unchanged occupancy.
__global__ __launch_bounds__(256, 4) void attn_kernel(
    const unsigned short* __restrict__ Qb, const unsigned short* __restrict__ Kb,
    const unsigned short* __restrict__ Vt, const unsigned short* __restrict__ maskbf,
    unsigned short* __restrict__ Ob)
{
  __shared__ alignas(16) char sK[2][8192];   // 64 x 64 bf16, swizzled rows
  __shared__ alignas(16) char sV[2][8192];   // 64(dv) x 64(c)
  const int tid = threadIdx.x, w = tid >> 6, l = tid & 63;
  const int g16 = l >> 4, c16 = l & 15;
  const int flat = blockIdx.x;                 // 768
  const int xcd = flat & 7, sidx = flat >> 3;  // sidx 0..95
  const int p = xcd + 8 * (sidx >> 5);         // panel 0..23
  const int qt = sidx & 31;
  const int h = p % 12, b = p / 12;
  const int qrow0 = b * SEQ + qt * 64;
  const int crow0 = b * SEQ;
  const int gLow = g16 >> 1, gOddB = (g16 & 1) * 8;

  bf16x8 qa[2];
  {
    const unsigned short* qp =
        Qb + (size_t)(qrow0 + w * 16 + c16) * D_MODEL + h * DKH + g16 * 8;
    qa[0] = *(const bf16x8*)(qp);
    qa[1] = *(const bf16x8*)(qp + 32);
  }

  auto stageK = [&](int ct, int buf) {
#pragma unroll
    for (int i = 0; i < 2; i++) {
      int ch = w * 2 + i;
      int X = ch * 1024 + l * 16;
      int row = X >> 7;
      int sl = ((X >> 4) & 7) ^ (row & 7);
      gld16(Kb + (size_t)(crow0 + ct + row) * D_MODEL + h * DKH + sl * 8,
            sK[buf] + ch * 1024);
    }
  };
  auto stageV = [&](int ct, int buf) {
#pragma unroll
    for (int i = 0; i < 2; i++) {
      int ch = w * 2 + i;
      int X = ch * 1024 + l * 16;
      int row = X >> 7;
      int sl = ((X >> 4) & 7) ^ (row & 7);
      gld16(Vt + (size_t)(h * DKH + row) * (size_t)MROWS + crow0 + ct + sl * 8,
            sV[buf] + ch * 1024);
    }
  };

  f32x4 accO[4], accL;
#pragma unroll
  for (int n = 0; n < 4; n++) accO[n] = f32x4{0.f, 0.f, 0.f, 0.f};
  accL = f32x4{0.f, 0.f, 0.f, 0.f};

  stageK(0, 0); stageV(0, 0);
  __syncthreads();
  int cur = 0;

  for (int ct = 0; ct < SEQ; ct += 64) {
    if (ct + 64 < SEQ) { stageK(ct + 64, cur ^ 1); stageV(ct + 64, cur ^ 1); }

    // mask fragments in the relabeled k-order: c(g,j) = 32kk+16*(j>>2)+4g+(j&3)
    bf16x8 mfrag[2];
#pragma unroll
    for (int kk = 0; kk < 2; kk++) {
      const unsigned short* mp = maskbf + crow0 + ct + kk * 32 + g16 * 4;
      bf16x4 m0 = *(const bf16x4*)(mp);        // c = 32kk+4g+{0..3}
      bf16x4 m1 = *(const bf16x4*)(mp + 16);   // c = 32kk+16+4g+{0..3}
      mfrag[kk] = __builtin_shufflevector(m0, m1, 0, 1, 2, 3, 4, 5, 6, 7);
    }

    // S^T = K Q^T (r9-verified): s4[n][r] = S[c = 16n+4g+r][q = w*16+c16]
    f32x4 s4[4];
#pragma unroll
    for (int n = 0; n < 4; n++) s4[n] = f32x4{0.f, 0.f, 0.f, 0.f};
    __builtin_amdgcn_s_setprio(1);
#pragma unroll
    for (int kk = 0; kk < 2; kk++) {
      bf16x8 kf[4];
#pragma unroll
      for (int n = 0; n < 4; n++) {
        int row = n * 16 + c16, slot = kk * 4 + g16;
        kf[n] = *(const bf16x8*)(sK[cur] + row * 128 + ((slot ^ (row & 7)) << 4));
      }
#pragma unroll
      for (int n = 0; n < 4; n++)
        s4[n] = __builtin_amdgcn_mfma_f32_16x16x32_bf16(kf[n], qa[kk], s4[n], 0, 0, 0);
    }
    __builtin_amdgcn_s_setprio(0);

    // p = exp2(s) in registers; pack A-frags lane-locally (no LDS)
    bf16x8 paf[2];
#pragma unroll
    for (int kk = 0; kk < 2; kk++)
#pragma unroll
      for (int j = 0; j < 4; j++) {
        paf[kk][j]     = (__bf16)__builtin_amdgcn_exp2f(s4[2 * kk][j]);
        paf[kk][j + 4] = (__bf16)__builtin_amdgcn_exp2f(s4[2 * kk + 1][j]);
      }

    // O += P * V(masked) ; L += P * maskfrag (relabeled k-order both sides)
    __builtin_amdgcn_s_setprio(1);
#pragma unroll
    for (int kk = 0; kk < 2; kk++) {
#pragma unroll
      for (int n = 0; n < 4; n++) {
        int row = n * 16 + c16;
        const char* base = sV[cur] + row * 128 + gOddB;
        int s1 = kk * 4 + gLow, s2 = s1 + 2;
        bf16x4 v0 = *(const bf16x4*)(base + ((s1 ^ (row & 7)) << 4));
        bf16x4 v1 = *(const bf16x4*)(base + ((s2 ^ (row & 7)) << 4));
        bf16x8 vf = __builtin_shufflevector(v0, v1, 0, 1, 2, 3, 4, 5, 6, 7);
        accO[n] = __builtin_amdgcn_mfma_f32_16x16x32_bf16(paf[kk], vf, accO[n], 0, 0, 0);
      }
      accL = __builtin_amdgcn_mfma_f32_16x16x32_bf16(paf[kk], mfrag[kk], accL, 0, 0, 0);
    }
    __builtin_amdgcn_s_setprio(0);

    __syncthreads();
    cur ^= 1;
  }

#pragma unroll
  for (int r = 0; r < 4; r++) {
    float inv = 1.0f / accL[r];
#pragma unroll
    for (int n = 0; n < 4; n++) {
      int row = qrow0 + w * 16 + g16 * 4 + r;
      int col = h * DKH + n * 16 + c16;
      Ob[(size_t)row * D_MODEL + col] = f2bf(accO[n][r] * inv);
    }
  }
}

// ---------------- launcher --------------------------------------------------
extern "C" void kernel_launch(void* const* d_in, const int* in_sizes, int n_in,
                              void* d_out, int out_size, void* d_ws, size_t ws_size,
                              hipStream_t stream) {
  const float* query   = (const float*)d_in[0];
  const float* context = (const float*)d_in[1];
  const int*   cmask   = (const int*)d_in[2];
  const float* Wq_w = (const float*)d_in[3];
  const float* Wq_b = (const float*)d_in[4];
  const float* Wk_w = (const float*)d_in[5];
  const float* Wk_b = (const float*)d_in[6];
  const float* Wv_w = (const float*)d_in[7];
  const float* Wv_b = (const float*)d_in[8];
  const float* fc_w = (const float*)d_in[9];
  const float* fc_b = (const float*)d_in[10];
  float* out = (float*)d_out;

  unsigned short* ws   = (unsigned short*)d_ws;
  const size_t NQ = (size_t)MROWS * D_MODEL;
  const size_t NW = (size_t)D_MODEL * D_MODEL;
  unsigned short* q_bf = ws;
  unsigned short* c_bf = q_bf + NQ;
  unsigned short* Qb   = c_bf + NQ;
  unsigned short* Kb   = Qb + NQ;
  unsigned short* Vtb  = Kb + NQ;
  unsigned short* Ob   = Vtb + NQ;
  unsigned short* wq   = Ob + NQ;
  unsigned short* wk   = wq + NW;
  unsigned short* wv   = wk + NW;
  unsigned short* wf   = wv + NW;
  // q_bf is dead after gemm_qkv; reuse its head for the bf16 mask vector
  unsigned short* maskbf = q_bf;   // 4096 bf16 = 8KB

  // one fused convert launch: q, c, 4 weights
  cvt_all<<<8448, 256, 0, stream>>>(query, context, Wq_w, Wk_w, Wv_w, fc_w,
                                    q_bf, c_bf, wq, wk, wv, wf);

  // Q/K/V projections fused: y=0 Q(scaled), y=1 K, y=2 V^T(col-masked)
  gemm_qkv<<<dim3(384, 3), 256, 0, stream>>>(
      q_bf, c_bf, wq, wk, wv, Wq_b, Wk_b, Wv_b, cmask, Qb, Kb, Vtb);

  // after gemm_qkv, q_bf is dead -> safe to overwrite with maskbf
  mask_bf<<<MROWS / 256, 256, 0, stream>>>(cmask, maskbf);

  attn_kernel<<<768, 256, 0, stream>>>(Qb, Kb, Vtb, maskbf, Ob);

  // out = O @ fc^T + fb (f32), 64x64 tiles, grid 768
  gemm_fc64<<<768, 256, 0, stream>>>(Ob, wf, fc_b, out);
}